// Round 8
// baseline (30.543 us; speedup 1.0000x reference)
//
#include <hip/hip_runtime.h>

#define NN 256
#define MM 512
#define INF_ 256
#define OUTF 128

// N1 "prep": 608 blocks x 256 thr.
//   blk 0..31  : emg blocks (b = blk>>4, mq = blk&15): recompute wa, h;
//                em cols [32mq,32mq+32) -> g slots 16mq..16mq+15 (dup +256);
//                S partials for high rows n in [128,256) -> Sp[b][mq][n-128].
//   blk 32..95 : low-row stats (4 rows/block): recompute ws = wa0+wa1,
//                cH pair per row, A half-counts -> rs0/rs1.
//   blk 96..607: H = X@W row (bn = blk-96), split-K over 2 thread-halves.
__global__ __launch_bounds__(256) void k_prep(const float* __restrict__ X,
                                              const float* __restrict__ A,
                                              const float* __restrict__ W,
                                              const float* __restrict__ avec,
                                              float* __restrict__ H,
                                              float* __restrict__ g,
                                              float* __restrict__ Sp,
                                              float* __restrict__ rs0,
                                              float* __restrict__ rs1) {
    const int blk = blockIdx.x;
    const int t = threadIdx.x;

    if (blk >= 96) {                      // ---------- H rows
        __shared__ float xs[INF_];
        __shared__ float accs[256];
        const int bn = blk - 96, f = t & 127, kh = t >> 7;
        xs[t] = X[bn * INF_ + t];
        __syncthreads();
        float acc = 0.f;
        const float* Wp = W + kh * 128 * OUTF + f;
        const float* xp = xs + kh * 128;
#pragma unroll 8
        for (int k = 0; k < 128; ++k) acc += xp[k] * Wp[k * OUTF];
        accs[t] = acc;
        __syncthreads();
        if (t < 128) H[bn * OUTF + t] = accs[t] + accs[t + 128];
        return;
    }

    if (blk < 32) {                       // ---------- emg
        const int b = blk >> 4, mq = blk & 15;
        const int c8 = t & 7, r8 = t >> 3;
        __shared__ float sa[2 * OUTF];
        __shared__ float swa0[INF_], swa1[INF_];
        __shared__ float sh0[NN], sh1[NN];
        __shared__ float sd[256], ss0[256], ss1[256];
        __shared__ float se0[32], se1[32], sg[16];
        sa[t] = avec[t];
        __syncthreads();
        // wa: 8 threads per W-row, 32 rows/pass, 8 passes; 128B segs coalesced
        for (int pass = 0; pass < 8; ++pass) {
            int k = pass * 32 + r8;
            const float4* Wr = (const float4*)(W + (size_t)k * OUTF) + c8 * 4;
            float w0 = 0.f, w1 = 0.f;
#pragma unroll
            for (int j = 0; j < 4; ++j) {
                float4 wv = Wr[j];
                int f0 = c8 * 16 + j * 4;
                w0 += wv.x*sa[f0] + wv.y*sa[f0+1] + wv.z*sa[f0+2] + wv.w*sa[f0+3];
                w1 += wv.x*sa[128+f0] + wv.y*sa[128+f0+1]
                    + wv.z*sa[128+f0+2] + wv.w*sa[128+f0+3];
            }
            w0 += __shfl_xor(w0, 1); w0 += __shfl_xor(w0, 2); w0 += __shfl_xor(w0, 4);
            w1 += __shfl_xor(w1, 1); w1 += __shfl_xor(w1, 2); w1 += __shfl_xor(w1, 4);
            if (c8 == 0) { swa0[k] = w0; swa1[k] = w1; }
        }
        __syncthreads();
        // h: 8 threads per X-row, 32 rows/pass, 8 passes
        for (int pass = 0; pass < 8; ++pass) {
            int n = pass * 32 + r8;
            const float4* Xr = (const float4*)(X + (size_t)(b * NN + n) * INF_) + c8 * 8;
            float h0v = 0.f, h1v = 0.f;
#pragma unroll
            for (int j = 0; j < 8; ++j) {
                float4 xv = Xr[j];
                int f0 = c8 * 32 + j * 4;
                h0v += xv.x*swa0[f0] + xv.y*swa0[f0+1]
                     + xv.z*swa0[f0+2] + xv.w*swa0[f0+3];
                h1v += xv.x*swa1[f0] + xv.y*swa1[f0+1]
                     + xv.z*swa1[f0+2] + xv.w*swa1[f0+3];
            }
            h0v += __shfl_xor(h0v, 1); h0v += __shfl_xor(h0v, 2); h0v += __shfl_xor(h0v, 4);
            h1v += __shfl_xor(h1v, 1); h1v += __shfl_xor(h1v, 2); h1v += __shfl_xor(h1v, 4);
            if (c8 == 0) { sh0[n] = h0v; sh1[n] = h1v; }
        }
        __syncthreads();
        // em for cols 32mq + (t&31), n-reduction split 8 ways
        {
            const int m_l = t & 31, n_l = t >> 5;
            const float* Ap = A + (size_t)b * NN * MM + mq * 32 + m_l;
            float d = 0.f, s0 = 0.f, s1 = 0.f;
#pragma unroll 8
            for (int i = 0; i < 32; ++i) {
                int n = n_l * 32 + i;
                float av = Ap[n * MM];
                d += av;
                s0 += av * sh0[n];
                s1 += av * sh1[n];
            }
            sd[t] = d; ss0[t] = s0; ss1[t] = s1;
        }
        __syncthreads();
        if (t < 32) {
            float D = 0.f, S0 = 0.f, S1 = 0.f;
#pragma unroll
            for (int j = 0; j < 8; ++j) {
                D  += sd[j * 32 + t];
                S0 += ss0[j * 32 + t];
                S1 += ss1[j * 32 + t];
            }
            if (D == 0.f) D = 1.f;
            se0[t] = S0 / D;
            se1[t] = S1 / D;
        }
        __syncthreads();
        if (t < 16) {
            float v = se0[2 * t] + se1[2 * t + 1];
            v = v > 0.f ? v : 0.01f * v;
            float gv = expf(v);
            g[b * MM + 16 * mq + t] = gv;
            g[b * MM + 256 + 16 * mq + t] = gv;
            sg[t] = gv;
        }
        __syncthreads();
        // S partials for high rows (private slot, no atomics)
        {
            const int u = t & 15, ng = t >> 4;
            const float gv = sg[u];
            const float* Alo = A + (size_t)b * NN * MM + 16 * mq + u;
#pragma unroll
            for (int step = 0; step < 8; ++step) {
                int n = 128 + ng + 16 * step;
                const float* Ar = Alo + (size_t)n * MM;
                float val = gv * (Ar[0] + Ar[256]);
                val += __shfl_xor(val, 1);
                val += __shfl_xor(val, 2);
                val += __shfl_xor(val, 4);
                val += __shfl_xor(val, 8);
                if (u == 0) Sp[b * 2048 + mq * 128 + (n - 128)] = val;
            }
        }
        return;
    }

    // ---------- low-row stats (blk 32..95)
    {
        const int lane = t & 63, wv = t >> 6;
        const int c8 = t & 7, r8 = t >> 3;
        __shared__ float sa2[OUTF];
        __shared__ float sws[INF_];
        if (t < 128) sa2[t] = avec[t] + avec[128 + t];
        __syncthreads();
        // ws = W @ (a0+a1): same 8-thread-per-row scheme
        for (int pass = 0; pass < 8; ++pass) {
            int k = pass * 32 + r8;
            const float4* Wr = (const float4*)(W + (size_t)k * OUTF) + c8 * 4;
            float w = 0.f;
#pragma unroll
            for (int j = 0; j < 4; ++j) {
                float4 wv = Wr[j];
                int f0 = c8 * 16 + j * 4;
                w += wv.x*sa2[f0] + wv.y*sa2[f0+1] + wv.z*sa2[f0+2] + wv.w*sa2[f0+3];
            }
            w += __shfl_xor(w, 1); w += __shfl_xor(w, 2); w += __shfl_xor(w, 4);
            if (c8 == 0) sws[k] = w;
        }
        __syncthreads();
        const int l = (blk - 32) * 4 + wv;      // 0..255
        const int b = l >> 7, n = l & 127;
        const int bn = b * NN + n;
        // cH for rows 2n, 2n+1: one float4 per lane, wave xor-reduce
        const float4* Xr0 = (const float4*)(X + (size_t)(b * NN + 2 * n) * INF_);
        const float4* Xr1 = (const float4*)(X + (size_t)(b * NN + 2 * n + 1) * INF_);
        float4 x0 = Xr0[lane], x1 = Xr1[lane];
        float hs0 = x0.x*sws[4*lane] + x0.y*sws[4*lane+1]
                  + x0.z*sws[4*lane+2] + x0.w*sws[4*lane+3];
        float hs1 = x1.x*sws[4*lane] + x1.y*sws[4*lane+1]
                  + x1.z*sws[4*lane+2] + x1.w*sws[4*lane+3];
#pragma unroll
        for (int off = 32; off >= 1; off >>= 1) {
            hs0 += __shfl_xor(hs0, off);
            hs1 += __shfl_xor(hs1, off);
        }
        float ch0 = hs0 > 0.f ? hs0 : 0.01f * hs0;
        float ch1 = hs1 > 0.f ? hs1 : 0.01f * hs1;
        // A half-row counts
        const float* Ar = A + (size_t)bn * MM;
        float c0 = 0.f, c1 = 0.f;
#pragma unroll
        for (int i = 0; i < 8; ++i) {
            float av = Ar[lane + 64 * i];
            if (i < 4) c0 += av; else c1 += av;
        }
#pragma unroll
        for (int off = 32; off >= 1; off >>= 1) {
            c0 += __shfl_xor(c0, off);
            c1 += __shfl_xor(c1, off);
        }
        if (lane == 0) {
            float mx = fmaxf(c0 > 0.f ? ch0 : -INFINITY,
                             c1 > 0.f ? ch1 : -INFINITY);
            float e0 = c0 > 0.f ? expf(ch0 - mx) : 0.f;
            float e1 = c1 > 0.f ? expf(ch1 - mx) : 0.f;
            float inv = 1.f / (c0 * e0 + c1 * e1);
            rs0[bn] = e0 * inv;
            rs1[bn] = e1 * inv;
        }
    }
}

// N2: out[b,m,f] = sum_{n<128} A*w*H + g[m] * sum_{n>=128} A*(1/S_n)*H.
// 512 blocks x 256 thr: block = (b, m-pair mp). S_n reduced from Sp inline.
__global__ __launch_bounds__(256) void k_out(const float* __restrict__ A,
                                             const float* __restrict__ H,
                                             const float* __restrict__ g,
                                             const float* __restrict__ rs0,
                                             const float* __restrict__ rs1,
                                             const float* __restrict__ Sp,
                                             float* __restrict__ out) {
    __shared__ float sW[NN], sA0[NN], sA1[NN];
    __shared__ float2 sacc[2][128];
    const int blk = blockIdx.x;
    const int b = blk >> 8, mp = blk & 255;
    const int t = threadIdx.x;
    const int m0 = 2 * mp, m1 = 2 * mp + 1;
    if (t < 128) {
        sW[t] = ((mp < 128) ? rs0 : rs1)[b * NN + t];   // low-row weight half
    } else {
        const float* sp = Sp + b * 2048 + (t - 128);
        float s = 0.f;
#pragma unroll
        for (int j = 0; j < 16; ++j) s += sp[j * 128];
        sW[t] = 1.f / s;                                // high-row 1/S_n
    }
    sA0[t] = A[((size_t)(b * NN + t)) * MM + m0];
    sA1[t] = A[((size_t)(b * NN + t)) * MM + m1];
    __syncthreads();
    const int f2 = t & 63;
    const int nh = (t >> 6) & 1;
    const int mh = t >> 7;
    const float* sA = mh ? sA1 : sA0;
    const float2* H2 = (const float2*)H + (size_t)b * NN * 64 + f2;
    float2 acc = {0.f, 0.f};
#pragma unroll 8
    for (int i = 0; i < 128; ++i) {
        int n = nh * 128 + i;
        float c = sA[n] * sW[n];            // LDS broadcasts
        float2 hv = H2[n * 64];             // coalesced 8B/lane
        acc.x = fmaf(c, hv.x, acc.x);
        acc.y = fmaf(c, hv.y, acc.y);
    }
    sacc[nh][mh * 64 + f2] = acc;
    __syncthreads();
    if (t < 128) {
        int mh2 = t >> 6, f2b = t & 63;
        int m = mp * 2 + mh2;
        float eE = g[b * MM + m];           // = exp(eLow[m])
        float2 lo = sacc[0][t];
        float2 hi = sacc[1][t];
        float2 r;
        r.x = lo.x + eE * hi.x;
        r.y = lo.y + eE * hi.y;
        ((float2*)out)[((size_t)b * MM + m) * 64 + f2b] = r;
    }
}

extern "C" void kernel_launch(void* const* d_in, const int* in_sizes, int n_in,
                              void* d_out, int out_size, void* d_ws, size_t ws_size,
                              hipStream_t stream) {
    const float* X = (const float*)d_in[0];
    const float* A = (const float*)d_in[1];
    const float* W = (const float*)d_in[2];
    const float* a = (const float*)d_in[3];
    float* out = (float*)d_out;
    float* ws = (float*)d_ws;

    float* H   = ws;            // B*N*OUTF = 65536
    float* g   = ws + 65536;    // B*M = 1024
    float* Sp  = ws + 66560;    // B*16*128 = 4096 (S partials per mq-block)
    float* rs0 = ws + 70656;    // B*N = 512 (low halves used)
    float* rs1 = ws + 71168;    // B*N = 512

    k_prep<<<608, 256, 0, stream>>>(X, A, W, a, H, g, Sp, rs0, rs1);
    k_out<<<512, 256, 0, stream>>>(A, H, g, rs0, rs1, Sp, out);
}

// Round 9
// 24.651 us; speedup vs baseline: 1.2390x; 1.2390x over previous
//
#include <hip/hip_runtime.h>

#define NN 256
#define MM 512
#define INF_ 256
#define OUTF 128

// N1: 256 blocks x 256 thr, TWO rows per block (shared W loads: 2 FMA/load).
// Per row: H = X@W, h0 = H.a0, h1 = H.a1, cH = leaky(h0+h1); rows n>=128
// zero S[b,n-128]. f = t&127, kh = t>>7 (split-K).
__global__ __launch_bounds__(256) void k_gemm(const float* __restrict__ X,
                                              const float* __restrict__ W,
                                              const float* __restrict__ avec,
                                              float* __restrict__ H,
                                              float* __restrict__ h0,
                                              float* __restrict__ h1,
                                              float* __restrict__ cH,
                                              float* __restrict__ S) {
    const int blk = blockIdx.x;          // 0..255
    const int t = threadIdx.x;
    const int f = t & 127, kh = t >> 7;
    const int bn0 = blk * 2, bn1 = bn0 + 1;
    __shared__ float xs[2][INF_];
    xs[0][t] = X[bn0 * INF_ + t];
    xs[1][t] = X[bn1 * INF_ + t];
    __syncthreads();
    float acc0 = 0.f, acc1 = 0.f;
    const float* Wp = W + kh * 128 * OUTF + f;
    const float* x0 = xs[0] + kh * 128;
    const float* x1 = xs[1] + kh * 128;
#pragma unroll 8
    for (int k = 0; k < 128; ++k) {
        float w = Wp[k * OUTF];          // coalesced; shared by both rows
        acc0 = fmaf(x0[k], w, acc0);
        acc1 = fmaf(x1[k], w, acc1);
    }
    __shared__ float accs[2][256];
    accs[0][t] = acc0;
    accs[1][t] = acc1;
    __syncthreads();
    // threads 0..127 own row0 feature t; 128..255 own row1 feature t-128
    const int r = t >> 7, tf = t & 127;
    const int bn = bn0 + r;
    float a2 = accs[r][tf] + accs[r][tf + 128];
    H[bn * OUTF + tf] = a2;
    float p0 = a2 * avec[tf];
    float p1 = a2 * avec[OUTF + tf];
#pragma unroll
    for (int off = 32; off >= 1; off >>= 1) {
        p0 += __shfl_down(p0, off);
        p1 += __shfl_down(p1, off);
    }
    __shared__ float r0[4], r1[4];
    const int wv = t >> 6, ln = t & 63;
    if (ln == 0) { r0[wv] = p0; r1[wv] = p1; }
    __syncthreads();
    if (ln == 0 && (wv & 1) == 0) {      // wv==0 -> row0, wv==2 -> row1
        float s0 = r0[wv] + r0[wv + 1];
        float s1 = r1[wv] + r1[wv + 1];
        h0[bn] = s0;
        h1[bn] = s1;
        float hA = s0 + s1;
        cH[bn] = hA > 0.f ? hA : 0.01f * hA;   // leaky_relu 0.01
        int n = bn & 255;
        if (n >= 128) S[(bn >> 8) * 128 + n - 128] = 0.f;
    }
}

// N2: 96 blocks (unchanged from the 26.6µs R7 version).
// Blocks 0..31 (b = blk>>4, mq = blk&15): em cols [32mq,32mq+32) -> g slots
//   16mq..16mq+15 (dup +256), then atomicAdd partial S[b,n] for high rows.
// Blocks 32..95: low-row (n<128) exact 2-value softmax weights -> rs0/rs1.
__global__ __launch_bounds__(256) void k_emg(const float* __restrict__ A,
                                             const float* __restrict__ h0,
                                             const float* __restrict__ h1,
                                             const float* __restrict__ cH,
                                             float* __restrict__ g,
                                             float* __restrict__ rs0,
                                             float* __restrict__ rs1,
                                             float* __restrict__ S) {
    const int blk = blockIdx.x;
    const int t = threadIdx.x;
    if (blk < 32) {
        const int b = blk >> 4, mq = blk & 15;
        const int m_l = t & 31, n_l = t >> 5;
        __shared__ float sh0[NN], sh1[NN];
        __shared__ float sd[256], ss0[256], ss1[256];
        __shared__ float se0[32], se1[32], sg[16];
        sh0[t] = h0[b * NN + t];
        sh1[t] = h1[b * NN + t];
        __syncthreads();
        const float* Ap = A + (size_t)b * NN * MM + mq * 32 + m_l;
        float d = 0.f, s0 = 0.f, s1 = 0.f;
#pragma unroll 8
        for (int i = 0; i < 32; ++i) {
            int n = n_l * 32 + i;
            float av = Ap[n * MM];          // coalesced across m_l
            d += av;
            s0 += av * sh0[n];
            s1 += av * sh1[n];
        }
        sd[t] = d; ss0[t] = s0; ss1[t] = s1;
        __syncthreads();
        if (t < 32) {
            float D = 0.f, S0 = 0.f, S1 = 0.f;
#pragma unroll
            for (int j = 0; j < 8; ++j) {
                D  += sd[j * 32 + t];
                S0 += ss0[j * 32 + t];
                S1 += ss1[j * 32 + t];
            }
            if (D == 0.f) D = 1.f;
            se0[t] = S0 / D;                // em0[32mq+t]
            se1[t] = S1 / D;                // em1[32mq+t]
        }
        __syncthreads();
        if (t < 16) {
            // g[16mq+u] = exp(leaky(em0[32mq+2u] + em1[32mq+2u+1]))
            float v = se0[2 * t] + se1[2 * t + 1];
            v = v > 0.f ? v : 0.01f * v;
            float gv = expf(v);
            g[b * MM + 16 * mq + t] = gv;
            g[b * MM + 256 + 16 * mq + t] = gv;
            sg[t] = gv;
        }
        __syncthreads();
        // S partials for high rows, local g only (order-independent atomics)
        {
            const int u = t & 15, ng = t >> 4;   // 16 col-lanes x 16 n-groups
            const float gv = sg[u];
            const float* Alo = A + (size_t)b * NN * MM + 16 * mq + u;
#pragma unroll
            for (int step = 0; step < 8; ++step) {
                int n = 128 + ng + 16 * step;
                const float* Ar = Alo + (size_t)n * MM;
                float val = gv * (Ar[0] + Ar[256]);
                val += __shfl_xor(val, 1);
                val += __shfl_xor(val, 2);
                val += __shfl_xor(val, 4);
                val += __shfl_xor(val, 8);
                if (u == 0) atomicAdd(&S[b * 128 + n - 128], val);
            }
        }
    } else {
        // low-row stats: l = (blk-32)*4 + wave -> b = l>>7, n = l&127
        const int wv = t >> 6, lane = t & 63;
        const int l = (blk - 32) * 4 + wv;
        const int b = l >> 7, n = l & 127;
        const int bn = b * NN + n;
        const float* Ar = A + (size_t)bn * MM;
        float c0 = 0.f, c1 = 0.f;
#pragma unroll
        for (int i = 0; i < 8; ++i) {
            float av = Ar[lane + 64 * i];
            if (i < 4) c0 += av; else c1 += av;
        }
#pragma unroll
        for (int off = 32; off >= 1; off >>= 1) {
            c0 += __shfl_xor(c0, off);
            c1 += __shfl_xor(c1, off);
        }
        if (lane == 0) {
            float ch0 = cH[b * NN + 2 * n];
            float ch1 = cH[b * NN + 2 * n + 1];
            float mx = fmaxf(c0 > 0.f ? ch0 : -INFINITY,
                             c1 > 0.f ? ch1 : -INFINITY);
            float e0 = c0 > 0.f ? expf(ch0 - mx) : 0.f;
            float e1 = c1 > 0.f ? expf(ch1 - mx) : 0.f;
            float inv = 1.f / (c0 * e0 + c1 * e1);
            rs0[bn] = e0 * inv;
            rs1[bn] = e1 * inv;
        }
    }
}

// N3: out[b,m,f] = sum_{n<128} A*w*H + g[m] * sum_{n>=128} A*(1/S_n)*H.
// 256 blocks x 256 thr, FOUR m-columns per block (H reads amortized 4x).
// b = blk>>7, mq = blk&127, m_base = 4*mq. Thread = (mh = t>>7 picks the
// m-pair, nh = (t>>6)&1 picks the n-half, f2 = t&63 float2-feature).
__global__ __launch_bounds__(256) void k_out(const float* __restrict__ A,
                                             const float* __restrict__ H,
                                             const float* __restrict__ g,
                                             const float* __restrict__ rs0,
                                             const float* __restrict__ rs1,
                                             const float* __restrict__ S,
                                             float* __restrict__ out) {
    __shared__ float sW[NN];
    __shared__ float sA[4][NN];
    __shared__ float2 sacc[2][4][64];
    const int blk = blockIdx.x;
    const int b = blk >> 7, mq = blk & 127;
    const int m_base = 4 * mq;
    const int t = threadIdx.x;
    if (t < 128) {
        sW[t] = ((mq < 64) ? rs0 : rs1)[b * NN + t];   // low-row weight half
    } else {
        sW[t] = 1.f / S[b * 128 + (t - 128)];          // high-row 1/S_n
    }
    const float* Ac = A + (size_t)(b * NN + t) * MM + m_base;
    sA[0][t] = Ac[0];
    sA[1][t] = Ac[1];
    sA[2][t] = Ac[2];
    sA[3][t] = Ac[3];
    __syncthreads();
    const int f2 = t & 63;
    const int nh = (t >> 6) & 1;
    const int mh = t >> 7;                 // pair {2mh, 2mh+1}
    const float* sA0 = sA[2 * mh];
    const float* sA1 = sA[2 * mh + 1];
    const float2* H2 = (const float2*)H + (size_t)b * NN * 64 + f2;
    float2 acc0 = {0.f, 0.f}, acc1 = {0.f, 0.f};
#pragma unroll 8
    for (int i = 0; i < 128; ++i) {
        int n = nh * 128 + i;
        float w = sW[n];                   // LDS broadcasts
        float2 hv = H2[n * 64];            // coalesced 8B/lane, L1-shared
        float c0 = sA0[n] * w;
        float c1 = sA1[n] * w;
        acc0.x = fmaf(c0, hv.x, acc0.x);
        acc0.y = fmaf(c0, hv.y, acc0.y);
        acc1.x = fmaf(c1, hv.x, acc1.x);
        acc1.y = fmaf(c1, hv.y, acc1.y);
    }
    sacc[nh][2 * mh][f2] = acc0;
    sacc[nh][2 * mh + 1][f2] = acc1;
    __syncthreads();
    // write: thread = (ml = t>>6, f2b = t&63)
    {
        const int ml = t >> 6, f2b = t & 63;
        const int m = m_base + ml;
        float eE = g[b * MM + m];          // = exp(eLow[m])
        float2 lo = sacc[0][ml][f2b];
        float2 hi = sacc[1][ml][f2b];
        float2 r;
        r.x = lo.x + eE * hi.x;
        r.y = lo.y + eE * hi.y;
        ((float2*)out)[((size_t)b * MM + m) * 64 + f2b] = r;
    }
}

extern "C" void kernel_launch(void* const* d_in, const int* in_sizes, int n_in,
                              void* d_out, int out_size, void* d_ws, size_t ws_size,
                              hipStream_t stream) {
    const float* X = (const float*)d_in[0];
    const float* A = (const float*)d_in[1];
    const float* W = (const float*)d_in[2];
    const float* a = (const float*)d_in[3];
    float* out = (float*)d_out;
    float* ws = (float*)d_ws;

    float* H   = ws;            // B*N*OUTF = 65536
    float* h0  = ws + 65536;    // 512
    float* h1  = ws + 66048;    // 512
    float* cH  = ws + 66560;    // 512
    float* g   = ws + 67072;    // B*M = 1024
    float* rs0 = ws + 68096;    // B*N = 512 (low halves used)
    float* rs1 = ws + 68608;    // B*N = 512
    float* S   = ws + 69120;    // B*128 = 256 (high-row softmax denominators)

    k_gemm<<<256, 256, 0, stream>>>(X, W, a, H, h0, h1, cH, S);
    k_emg<<<96, 256, 0, stream>>>(A, h0, h1, cH, g, rs0, rs1, S);
    k_out<<<256, 256, 0, stream>>>(A, H, g, rs0, rs1, S, out);
}